// Round 1
// 2016.877 us; speedup vs baseline: 1.0445x; 1.0445x over previous
//
#include <hip/hip_runtime.h>
#include <hip/hip_bf16.h>

#define NNODES 40000
#define NEDGE  60000
#define NCYC5  30000
#define NCYC6  25000
#define EROWS  (2*NEDGE)    // 120000
#define C5ROWS (5*NCYC5)    // 150000
#define C6ROWS (6*NCYC6)    // 150000

typedef __attribute__((ext_vector_type(8))) short short8;   // 8 bf16 lanes
typedef __attribute__((ext_vector_type(4))) float f32x4;

__device__ __forceinline__ short f2bs(float x){
  union { __hip_bfloat16 h; short s; } u; u.h = __float2bfloat16(x); return u.s;
}
__device__ __forceinline__ float bs2f(short s){
  union { short s; __hip_bfloat16 h; } u; u.s = s; return __bfloat162float(u.h);
}

// rows m and m^1 live in adjacent lanes (l15 pairs): piece3 = val(m)+val(m^1)
__device__ __forceinline__ short8 combine_pair(short8 a){
  union U { short8 v; int i[4]; } u, w;
  u.v = a;
  #pragma unroll
  for (int j = 0; j < 4; ++j) w.i[j] = __shfl_xor(u.i[j], 1);
  short8 r;
  #pragma unroll
  for (int j = 0; j < 8; ++j) r[j] = f2bs(bs2f(a[j]) + bs2f(w.v[j]));
  return r;
}

// ---------------- CSR build ----------------
__global__ void hist_k(const int* __restrict__ atoms, int* __restrict__ deg, int n){
  int r = blockIdx.x*256 + threadIdx.x;
  if (r < n) atomicAdd(&deg[atoms[r]], 1);
}

// 3 blocks, 1024 threads each: exclusive scan of one deg array per block
__global__ void scan3_k(const int* __restrict__ d0, const int* __restrict__ d1,
                        const int* __restrict__ d2, int* __restrict__ o0,
                        int* __restrict__ o1, int* __restrict__ o2){
  const int* deg = blockIdx.x==0 ? d0 : (blockIdx.x==1 ? d1 : d2);
  int* offs      = blockIdx.x==0 ? o0 : (blockIdx.x==1 ? o1 : o2);
  const int N = NNODES;
  __shared__ int part[1024];
  int tid = threadIdx.x;
  const int chunk = (N + 1023) / 1024;
  int lo = tid*chunk, hi = min(lo+chunk, N);
  int s = 0;
  for (int i = lo; i < hi; ++i) s += deg[i];
  part[tid] = s;
  __syncthreads();
  for (int d = 1; d < 1024; d <<= 1){
    int v = (tid >= d) ? part[tid-d] : 0;
    __syncthreads();
    part[tid] += v;
    __syncthreads();
  }
  int pref = (tid == 0) ? 0 : part[tid-1];
  for (int i = lo; i < hi; ++i){ offs[i] = pref; pref += deg[i]; }
  if (tid == 1023) offs[N] = part[1023];
}

__global__ void fill_k(const int* __restrict__ atoms, const int* __restrict__ offs,
                       int* __restrict__ cursor, int* __restrict__ rows, int n){
  int r = blockIdx.x*256 + threadIdx.x;
  if (r < n){ int a = atoms[r]; rows[offs[a] + atomicAdd(&cursor[a],1)] = r; }
}

// ---------------- gather stages (CSR, no atomics) ----------------
template<int CW, int RDIV, int ACC, int INB, int OUTB>
__global__ void gath_k(const void* __restrict__ srcv, const int* __restrict__ offs,
                       const int* __restrict__ rows, void* __restrict__ dstv,
                       int OS, int OFF){
  int t = blockIdx.x*256 + threadIdx.x;
  if (t >= NNODES*CW) return;
  int n = t / CW, ch = t - n*CW;
  int o = offs[n], e = offs[n+1];
  float s = 0.f;
  for (int i = o; i < e; ++i){
    int r = rows[i];
    size_t si = (size_t)(r / RDIV) * CW + ch;
    s += INB ? bs2f(((const short*)srcv)[si]) : ((const float*)srcv)[si];
  }
  size_t di = (size_t)n*OS + OFF + ch;
  if (OUTB){ short* d = (short*)dstv; d[di] = f2bs((ACC ? bs2f(d[di]) : 0.f) + s); }
  else     { float* d = (float*)dstv; d[di] = (ACC ? d[di] : 0.f) + s; }
}

// S1[c][ch] = sum_j node_e[atom[c*R+j]][ch]   (fp32)
template<int R>
__global__ void s1_k(const float* __restrict__ node_e, const int* __restrict__ atoms,
                     float* __restrict__ S1, int C){
  int t = blockIdx.x*256 + threadIdx.x;
  if (t >= C*64) return;
  int c = t >> 6, ch = t & 63;
  const int* ap = atoms + c*R;
  float s = 0.f;
  #pragma unroll
  for (int j = 0; j < R; ++j) s += node_e[(size_t)ap[j]*64 + ch];
  S1[t] = s;
}

// n5h[n][0:64] = deg[n]*node_e[n]  (bf16 out)
__global__ void n5lo_k(const float* __restrict__ node_e, const int* __restrict__ offs,
                       short* __restrict__ n5h){
  int t = blockIdx.x*256 + threadIdx.x;
  if (t >= NNODES*64) return;
  int n = t >> 6, ch = t & 63;
  float d = (float)(offs[n+1] - offs[n]);
  n5h[(size_t)n*128 + ch] = f2bs(d * node_e[(size_t)n*64 + ch]);
}

// S2h[c][ch] = sum_j n5h[atom[c*R+j]][ch]  (bf16 in/out, fp32 sum)
template<int R>
__global__ void s2_k(const short* __restrict__ n5h, const int* __restrict__ atoms,
                     short* __restrict__ S2h, int C){
  int t = blockIdx.x*256 + threadIdx.x;
  if (t >= C*128) return;
  int c = t >> 7, ch = t & 127;
  const int* ap = atoms + c*R;
  float s = 0.f;
  #pragma unroll
  for (int j = 0; j < R; ++j) s += bs2f(n5h[(size_t)ap[j]*128 + ch]);
  S2h[t] = f2bs(s);
}

// nodeC_h[n][0:128] = deg5*n5_5 + deg6*n5_6
__global__ void nc0_k(const short* __restrict__ n5, const short* __restrict__ n6,
                      const int* __restrict__ o5, const int* __restrict__ o6,
                      short* __restrict__ nodeC){
  int t = blockIdx.x*256 + threadIdx.x;
  if (t >= NNODES*128) return;
  int n = t >> 7;
  float d5 = (float)(o5[n+1]-o5[n]), d6 = (float)(o6[n+1]-o6[n]);
  nodeC[(size_t)n*320 + (t & 127)] = f2bs(d5*bs2f(n5[t]) + d6*bs2f(n6[t]));
}

// fp32 -> bf16 stream convert (n4 = count/4)
__global__ void f2h_k(const float* __restrict__ src, short* __restrict__ dst, int n4){
  int t = blockIdx.x*256 + threadIdx.x;
  if (t >= n4) return;
  float4 v = ((const float4*)src)[t];
  short4 o; o.x=f2bs(v.x); o.y=f2bs(v.y); o.z=f2bs(v.z); o.w=f2bs(v.w);
  ((short4*)dst)[t] = o;
}

// WT[n][k] = bf16(W[k][n]);  W fp32 [K][N], N=1<<logN
__global__ void tr_k(const float* __restrict__ W, short* __restrict__ WT, int K, int logN){
  int t = blockIdx.x*256 + threadIdx.x;
  if (t >= (K << logN)) return;
  int k = t >> logN, n = t & ((1<<logN)-1);
  WT[(size_t)n*K + k] = f2bs(W[t]);
}

// scale/shift for BN fusion: y = scale[ch]*x + shift[ch]
__global__ void mkscale_k(const float* __restrict__ ssum, const float* __restrict__ ssq,
                          const float* __restrict__ g, const float* __restrict__ b,
                          float* __restrict__ scale, float* __restrict__ shift, int M){
  int ch = threadIdx.x;
  float inv  = 1.f / (float)M;
  float mean = ssum[ch]*inv;
  float var  = fmaxf(ssq[ch]*inv - mean*mean, 0.f);
  float sc   = g[ch] * rsqrtf(var + 1e-5f);
  scale[ch] = sc; shift[ch] = b[ch] - mean*sc;
}

// final BatchNorm+ReLU on fp32 d_out (C=64), in place
__global__ void bnf_k(float* __restrict__ X, const float* __restrict__ ssum,
                      const float* __restrict__ ssq, const float* __restrict__ g,
                      const float* __restrict__ b, int M){
  int t = blockIdx.x*256 + threadIdx.x;
  if (t >= M*64) return;
  int ch = t & 63;
  float inv  = 1.f / (float)M;
  float mean = ssum[ch]*inv;
  float var  = fmaxf(ssq[ch]*inv - mean*mean, 0.f);
  float sc   = g[ch] * rsqrtf(var + 1e-5f);
  X[t] = fmaxf(sc*X[t] + (b[ch] - mean*sc), 0.f);
}

// ---------------- MFMA GEMM, latency-hiding rewrite ----------------
// Changes vs previous version (which was latency-bound: MfmaUtil 3%, HBM 3.7%):
//  1. ALL gathered A-fragments prefetched into registers up-front
//     (10-12 independent global loads -> one exposed latency, not a chain).
//  2. B (BT) staged through LDS in 32-k slices, double-buffered LDS +
//     depth-2 register pipeline: MFMA B-reads become ds_read_b128 and
//     B traffic drops from per-wave to per-block.
//  3. 16B chunk slots XOR-swizzled (c ^ ((n>>1)&3)) so the fragment
//     ds_read pattern (16 rows @ 64B stride) is bank-conflict-free.
// LOADER 1: edge rows  [ef_h(64) | nodeC_h[aS](320) | shfl-combined(320)], KC=704
// LOADER 2: cycle rows [n5h[aS](128) | S2h[m/RDIV](128) | featsh(64)],    KC=320
// LOADER 3: bf16 A with fused per-k affine+ReLU (BN1), KC=128
template<int LOADER, int NT, int OUTF32, int KC, int RDIV>
__global__ __launch_bounds__(256) void gemm_k(
    const short* __restrict__ A, const short* __restrict__ G0,
    const short* __restrict__ G1, const float* __restrict__ F0,
    const float* __restrict__ F1, const int* __restrict__ atoms,
    const short* __restrict__ BT, void* __restrict__ CoutV,
    float* __restrict__ ssum, float* __restrict__ ssq, int M)
{
  constexpr int NK = KC/32;          // k-slices
  constexpr int NC = NT*16;          // output cols = BT rows staged
  constexpr int CH = (NC*4)/256;     // 16B chunks per thread per slice
  __shared__ short lds[2*NC*32];     // 2 slice buffers

  const int wv   = threadIdx.x >> 6;
  const int lane = threadIdx.x & 63;
  const int row0 = blockIdx.x*64 + wv*16;
  const int l15 = lane & 15, quad = lane >> 4;
  // whole waves can be out of range (M % 16 == 0 for all call sites), but
  // they must still participate in staging + barriers
  const bool act = (row0 < M);
  const int m = act ? (row0 + l15) : 0;

  int aS = 0, cyc = 0;
  if (LOADER == 1) aS = act ? atoms[m] : 0;
  if (LOADER == 2) { aS = act ? atoms[m] : 0; cyc = m / RDIV; }

  // ---- A prefetch: issue every gathered fragment load now ----
  constexpr int NLD = (LOADER==1) ? 12 : (LOADER==2 ? 10 : NK);
  short8 af[NLD];
  if (act) {
    #pragma unroll
    for (int kt = 0; kt < NLD; ++kt) {
      const int k0 = kt*32 + quad*8;
      if (LOADER == 1) {
        if (kt < 2) af[kt] = *reinterpret_cast<const short8*>(A + (size_t)m*64 + k0);
        else        af[kt] = *reinterpret_cast<const short8*>(G0 + (size_t)aS*320 + (k0-64));
      } else if (LOADER == 2) {
        if (kt < 4)      af[kt] = *reinterpret_cast<const short8*>(G0 + (size_t)aS*128 + k0);
        else if (kt < 8) af[kt] = *reinterpret_cast<const short8*>(G1 + (size_t)cyc*128 + (k0-128));
        else             af[kt] = *reinterpret_cast<const short8*>(A + (size_t)m*64 + (k0-256));
      } else { // LOADER 3: raw rows, BN affine applied at use
        af[kt] = *reinterpret_cast<const short8*>(A + (size_t)m*KC + k0);
      }
    }
  }

  // ---- B slice staging helpers (all 256 threads) ----
  auto stage_load = [&](int kt, short8* r){
    #pragma unroll
    for (int i = 0; i < CH; ++i) {
      int id = i*256 + (int)threadIdx.x;        // chunk id: n = id>>2, c = id&3
      r[i] = *reinterpret_cast<const short8*>(BT + (size_t)(id>>2)*KC + kt*32 + (id&3)*8);
    }
  };
  auto stage_write = [&](int b, short8* r){
    #pragma unroll
    for (int i = 0; i < CH; ++i) {
      int id = i*256 + (int)threadIdx.x;
      int n = id>>2, c = id&3;
      *reinterpret_cast<short8*>(&lds[b*NC*32 + n*32 + ((c ^ ((n>>1)&3)))*8]) = r[i];
    }
  };

  f32x4 acc[NT];
  #pragma unroll
  for (int nt = 0; nt < NT; ++nt) acc[nt] = (f32x4){0.f,0.f,0.f,0.f};

  // depth-2 pipeline: slices kt and kt+1 in flight in registers
  short8 sr0[CH], sr1[CH], sr2[CH];
  stage_load(0, sr0);
  if (NK > 1) stage_load(1, sr1);

  #pragma unroll
  for (int kt = 0; kt < NK; ++kt) {
    // write slice kt (loaded 2 iterations ago) to LDS buf kt&1
    short8* cur = (kt % 3 == 0) ? sr0 : ((kt % 3 == 1) ? sr1 : sr2);
    stage_write(kt & 1, cur);
    if (kt + 2 < NK) {
      short8* nxt = ((kt+2) % 3 == 0) ? sr0 : (((kt+2) % 3 == 1) ? sr1 : sr2);
      stage_load(kt + 2, nxt);
    }
    __syncthreads();

    if (act) {
      const int k0 = kt*32 + quad*8;
      short8 afk;
      {
        short8 base = af[(kt < NLD) ? kt : (kt - 10)];
        if (LOADER == 3) {
          float sc[8], sh[8];
          const float4* sp = reinterpret_cast<const float4*>(F0 + k0);
          const float4* hp = reinterpret_cast<const float4*>(F1 + k0);
          *reinterpret_cast<float4*>(&sc[0]) = sp[0]; *reinterpret_cast<float4*>(&sc[4]) = sp[1];
          *reinterpret_cast<float4*>(&sh[0]) = hp[0]; *reinterpret_cast<float4*>(&sh[4]) = hp[1];
          #pragma unroll
          for (int j = 0; j < 8; ++j) afk[j] = f2bs(fmaxf(sc[j]*bs2f(base[j]) + sh[j], 0.f));
        } else if (LOADER == 1 && kt >= 12) {
          afk = combine_pair(base);
        } else {
          afk = base;
        }
      }
      #pragma unroll
      for (int nt = 0; nt < NT; ++nt) {
        const int n = nt*16 + l15;
        const short8 bfg = *reinterpret_cast<const short8*>(
            &lds[(kt&1)*NC*32 + n*32 + ((quad ^ ((n>>1)&3)))*8]);
        acc[nt] = __builtin_amdgcn_mfma_f32_16x16x32_bf16(afk, bfg, acc[nt], 0, 0, 0);
      }
    }
    // no trailing barrier needed: next iteration writes the OTHER LDS buffer,
    // and the following write of THIS buffer is separated by the next barrier
  }

  if (!act) return;

  #pragma unroll
  for (int nt = 0; nt < NT; ++nt) {
    float ps = 0.f, pq = 0.f;
    #pragma unroll
    for (int rg = 0; rg < 4; ++rg) {
      float v = acc[nt][rg];                       // D[row=quad*4+rg][col=l15]
      int r = row0 + quad*4 + rg;
      if (OUTF32) ((float*)CoutV)[(size_t)r*NC + nt*16 + l15] = v;
      else        ((short*)CoutV)[(size_t)r*NC + nt*16 + l15] = f2bs(v);
      ps += v; pq += v*v;
    }
    ps += __shfl_xor(ps, 16); pq += __shfl_xor(pq, 16);
    ps += __shfl_xor(ps, 32); pq += __shfl_xor(pq, 32);
    if (quad == 0) {
      atomicAdd(&ssum[nt*16 + l15], ps);
      atomicAdd(&ssq [nt*16 + l15], pq);
    }
  }
}

static inline int cdiv(int a, int b){ return (a + b - 1)/b; }

extern "C" void kernel_launch(void* const* d_in, const int* in_sizes, int n_in,
                              void* d_out, int out_size, void* d_ws, size_t ws_size,
                              hipStream_t stream)
{
  const float* edge_feats = (const float*)d_in[0];
  const float* c5_feats   = (const float*)d_in[1];
  const float* c6_feats   = (const float*)d_in[2];
  const int*   e_atoms    = (const int*)d_in[3];
  const int*   c5_atoms   = (const int*)d_in[4];
  const int*   c6_atoms   = (const int*)d_in[5];
  const float* eW1 = (const float*)d_in[6];
  const float* eg1 = (const float*)d_in[7];
  const float* eb1 = (const float*)d_in[8];
  const float* eW2 = (const float*)d_in[9];
  const float* eg2 = (const float*)d_in[10];
  const float* eb2 = (const float*)d_in[11];
  const float* cW1 = (const float*)d_in[12];
  const float* cg1 = (const float*)d_in[13];
  const float* cb1 = (const float*)d_in[14];
  const float* cW2 = (const float*)d_in[15];
  const float* cg2 = (const float*)d_in[16];
  const float* cb2 = (const float*)d_in[17];
  float* out = (float*)d_out;
  (void)in_sizes; (void)n_in; (void)out_size; (void)ws_size;

  char* w = (char*)d_ws;
  auto alloc = [&](size_t bytes) -> char* {
    char* p = w; w += (bytes + 255) & ~(size_t)255; return p;
  };

  // ---- zero zone (~1 MB): histograms, cursors, stats ----
  char* zbase = w;
  int*  deg_e = (int*)alloc(NNODES*4);
  int*  deg_5 = (int*)alloc(NNODES*4);
  int*  deg_6 = (int*)alloc(NNODES*4);
  int*  cur_e = (int*)alloc(NNODES*4);
  int*  cur_5 = (int*)alloc(NNODES*4);
  int*  cur_6 = (int*)alloc(NNODES*4);
  float* stats = (float*)alloc(1152*4);
  size_t zbytes = (size_t)(w - zbase);

  float* se1 = stats;        float* qe1 = stats + 128;
  float* se2 = stats + 256;  float* qe2 = stats + 320;
  float* s51 = stats + 384;  float* q51 = stats + 512;
  float* s52 = stats + 640;  float* q52 = stats + 704;
  float* s61 = stats + 768;  float* q61 = stats + 896;
  float* s62 = stats + 1024; float* q62 = stats + 1088;

  // ---- write-before-read buffers ----
  int* offs_e = (int*)alloc((NNODES+1)*4);
  int* offs_5 = (int*)alloc((NNODES+1)*4);
  int* offs_6 = (int*)alloc((NNODES+1)*4);
  int* rows_e = (int*)alloc((size_t)EROWS*4);
  int* rows_5 = (int*)alloc((size_t)C5ROWS*4);
  int* rows_6 = (int*)alloc((size_t)C6ROWS*4);
  short* nodeC_h = (short*)alloc((size_t)NNODES*320*2);   // 25.6 MB
  short* n5_5h   = (short*)alloc((size_t)NNODES*128*2);   // 10.24 MB
  short* n5_6h   = (short*)alloc((size_t)NNODES*128*2);
  short* S2_5h   = (short*)alloc((size_t)NCYC5*128*2);    // 7.68 MB
  short* S2_6h   = (short*)alloc((size_t)NCYC6*128*2);    // 6.4 MB
  short* ef_h    = (short*)alloc((size_t)EROWS*64*2);     // 15.36 MB
  short* c5f_h   = (short*)alloc((size_t)C5ROWS*64*2);    // 19.2 MB
  short* c6f_h   = (short*)alloc((size_t)C6ROWS*64*2);    // 19.2 MB
  short* eW1T    = (short*)alloc((size_t)128*704*2);
  short* cW1T    = (short*)alloc((size_t)128*320*2);
  short* eW2T    = (short*)alloc((size_t)64*128*2);
  short* cW2T    = (short*)alloc((size_t)64*128*2);
  float* scsh    = (float*)alloc(768*4);                  // 3x (scale128, shift128)
  float* sc_e = scsh;       float* sh_e = scsh + 128;
  float* sc_5 = scsh + 256; float* sh_5 = scsh + 384;
  float* sc_6 = scsh + 512; float* sh_6 = scsh + 640;
  // h1 region (38.4 MB) shared by 3 MLPs; phase-1 fp32 temporaries alias it
  char*  h1reg = alloc((size_t)C5ROWS*128*2);
  short* h1    = (short*)h1reg;
  float* node_e = (float*)h1reg;                                          // 10.24 MB
  float* S1_5   = (float*)(h1reg + (size_t)NNODES*64*4);                  // 7.68 MB
  float* S1_6   = (float*)(h1reg + (size_t)NNODES*64*4 + (size_t)NCYC5*64*4); // 6.4 MB
  // total ws ~156 MB

  hipMemsetAsync(zbase, 0, zbytes, stream);

  // ---- CSR build ----
  hist_k<<<cdiv(EROWS,256),256,0,stream>>>(e_atoms, deg_e, EROWS);
  hist_k<<<cdiv(C5ROWS,256),256,0,stream>>>(c5_atoms, deg_5, C5ROWS);
  hist_k<<<cdiv(C6ROWS,256),256,0,stream>>>(c6_atoms, deg_6, C6ROWS);
  scan3_k<<<3,1024,0,stream>>>(deg_e, deg_5, deg_6, offs_e, offs_5, offs_6);
  fill_k<<<cdiv(EROWS,256),256,0,stream>>>(e_atoms, offs_e, cur_e, rows_e, EROWS);
  fill_k<<<cdiv(C5ROWS,256),256,0,stream>>>(c5_atoms, offs_5, cur_5, rows_5, C5ROWS);
  fill_k<<<cdiv(C6ROWS,256),256,0,stream>>>(c6_atoms, offs_6, cur_6, rows_6, C6ROWS);

  // ---- bf16 copies of GEMM A-row sources ----
  f2h_k<<<cdiv(EROWS*16,256),256,0,stream>>>(edge_feats, ef_h, EROWS*16);
  f2h_k<<<cdiv(C5ROWS*16,256),256,0,stream>>>(c5_feats, c5f_h, C5ROWS*16);
  f2h_k<<<cdiv(C6ROWS*16,256),256,0,stream>>>(c6_feats, c6f_h, C6ROWS*16);

  // ---- phase 1: node/cycle aggregates (gather, no atomics) ----
  gath_k<64,1,0,0,0><<<cdiv(NNODES*64,256),256,0,stream>>>(edge_feats, offs_e, rows_e, node_e, 64, 0);
  s1_k<5><<<cdiv(NCYC5*64,256),256,0,stream>>>(node_e, c5_atoms, S1_5, NCYC5);
  s1_k<6><<<cdiv(NCYC6*64,256),256,0,stream>>>(node_e, c6_atoms, S1_6, NCYC6);
  n5lo_k<<<cdiv(NNODES*64,256),256,0,stream>>>(node_e, offs_5, n5_5h);
  n5lo_k<<<cdiv(NNODES*64,256),256,0,stream>>>(node_e, offs_6, n5_6h);
  gath_k<64,5,0,0,1><<<cdiv(NNODES*64,256),256,0,stream>>>(S1_5, offs_5, rows_5, n5_5h, 128, 64);
  gath_k<64,6,0,0,1><<<cdiv(NNODES*64,256),256,0,stream>>>(S1_6, offs_6, rows_6, n5_6h, 128, 64);
  s2_k<5><<<cdiv(NCYC5*128,256),256,0,stream>>>(n5_5h, c5_atoms, S2_5h, NCYC5);
  s2_k<6><<<cdiv(NCYC6*128,256),256,0,stream>>>(n5_6h, c6_atoms, S2_6h, NCYC6);
  nc0_k<<<cdiv(NNODES*128,256),256,0,stream>>>(n5_5h, n5_6h, offs_5, offs_6, nodeC_h);
  gath_k<128,5,0,1,1><<<cdiv(NNODES*128,256),256,0,stream>>>(S2_5h, offs_5, rows_5, nodeC_h, 320, 128);
  gath_k<128,6,1,1,1><<<cdiv(NNODES*128,256),256,0,stream>>>(S2_6h, offs_6, rows_6, nodeC_h, 320, 128);
  gath_k<64,1,0,0,1><<<cdiv(NNODES*64,256),256,0,stream>>>(c5_feats, offs_5, rows_5, nodeC_h, 320, 256);
  gath_k<64,1,1,0,1><<<cdiv(NNODES*64,256),256,0,stream>>>(c6_feats, offs_6, rows_6, nodeC_h, 320, 256);

  // ---- weight transposes ----
  tr_k<<<cdiv(704*128,256),256,0,stream>>>(eW1, eW1T, 704, 7);
  tr_k<<<cdiv(320*128,256),256,0,stream>>>(cW1, cW1T, 320, 7);
  tr_k<<<cdiv(128*64,256),256,0,stream>>>(eW2, eW2T, 128, 6);
  tr_k<<<cdiv(128*64,256),256,0,stream>>>(cW2, cW2T, 128, 6);

  float* out_e = out;
  float* out_5 = out + (size_t)EROWS*64;
  float* out_6 = out + (size_t)(EROWS + C5ROWS)*64;

  // ---- edge MLP ----
  gemm_k<1,8,0,704,1><<<cdiv(EROWS,64),256,0,stream>>>(ef_h, nodeC_h, nullptr, nullptr, nullptr,
                                                       e_atoms, eW1T, h1, se1, qe1, EROWS);
  mkscale_k<<<1,128,0,stream>>>(se1, qe1, eg1, eb1, sc_e, sh_e, EROWS);
  gemm_k<3,4,1,128,1><<<cdiv(EROWS,64),256,0,stream>>>(h1, nullptr, nullptr, sc_e, sh_e,
                                                       nullptr, eW2T, out_e, se2, qe2, EROWS);
  bnf_k<<<cdiv(EROWS*64,256),256,0,stream>>>(out_e, se2, qe2, eg2, eb2, EROWS);

  // ---- cycle5 MLP ----
  gemm_k<2,8,0,320,5><<<cdiv(C5ROWS,64),256,0,stream>>>(c5f_h, n5_5h, S2_5h, nullptr, nullptr,
                                                        c5_atoms, cW1T, h1, s51, q51, C5ROWS);
  mkscale_k<<<1,128,0,stream>>>(s51, q51, cg1, cb1, sc_5, sh_5, C5ROWS);
  gemm_k<3,4,1,128,1><<<cdiv(C5ROWS,64),256,0,stream>>>(h1, nullptr, nullptr, sc_5, sh_5,
                                                        nullptr, cW2T, out_5, s52, q52, C5ROWS);
  bnf_k<<<cdiv(C5ROWS*64,256),256,0,stream>>>(out_5, s52, q52, cg2, cb2, C5ROWS);

  // ---- cycle6 MLP ----
  gemm_k<2,8,0,320,6><<<cdiv(C6ROWS,64),256,0,stream>>>(c6f_h, n5_6h, S2_6h, nullptr, nullptr,
                                                        c6_atoms, cW1T, h1, s61, q61, C6ROWS);
  mkscale_k<<<1,128,0,stream>>>(s61, q61, cg1, cb1, sc_6, sh_6, C6ROWS);
  gemm_k<3,4,1,128,1><<<cdiv(C6ROWS,64),256,0,stream>>>(h1, nullptr, nullptr, sc_6, sh_6,
                                                        nullptr, cW2T, out_6, s62, q62, C6ROWS);
  bnf_k<<<cdiv(C6ROWS*64,256),256,0,stream>>>(out_6, s62, q62, cg2, cb2, C6ROWS);
}

// Round 2
// 1035.881 us; speedup vs baseline: 2.0336x; 1.9470x over previous
//
#include <hip/hip_runtime.h>
#include <hip/hip_bf16.h>

#define NNODES 40000
#define NEDGE  60000
#define NCYC5  30000
#define NCYC6  25000
#define EROWS  (2*NEDGE)    // 120000
#define C5ROWS (5*NCYC5)    // 150000
#define C6ROWS (6*NCYC6)    // 150000

typedef __attribute__((ext_vector_type(8))) short short8;   // 8 bf16 lanes
typedef __attribute__((ext_vector_type(4))) float f32x4;

__device__ __forceinline__ short f2bs(float x){
  union { __hip_bfloat16 h; short s; } u; u.h = __float2bfloat16(x); return u.s;
}
__device__ __forceinline__ float bs2f(short s){
  union { short s; __hip_bfloat16 h; } u; u.s = s; return __bfloat162float(u.h);
}

// rows m and m^1 live in adjacent lanes (l15 pairs): piece3 = val(m)+val(m^1)
__device__ __forceinline__ short8 combine_pair(short8 a){
  union U { short8 v; int i[4]; } u, w;
  u.v = a;
  #pragma unroll
  for (int j = 0; j < 4; ++j) w.i[j] = __shfl_xor(u.i[j], 1);
  short8 r;
  #pragma unroll
  for (int j = 0; j < 8; ++j) r[j] = f2bs(bs2f(a[j]) + bs2f(w.v[j]));
  return r;
}

// ---------------- CSR build ----------------
__global__ void hist_k(const int* __restrict__ atoms, int* __restrict__ deg, int n){
  int r = blockIdx.x*256 + threadIdx.x;
  if (r < n) atomicAdd(&deg[atoms[r]], 1);
}

// 3 blocks, 1024 threads each: exclusive scan of one deg array per block
__global__ void scan3_k(const int* __restrict__ d0, const int* __restrict__ d1,
                        const int* __restrict__ d2, int* __restrict__ o0,
                        int* __restrict__ o1, int* __restrict__ o2){
  const int* deg = blockIdx.x==0 ? d0 : (blockIdx.x==1 ? d1 : d2);
  int* offs      = blockIdx.x==0 ? o0 : (blockIdx.x==1 ? o1 : o2);
  const int N = NNODES;
  __shared__ int part[1024];
  int tid = threadIdx.x;
  const int chunk = (N + 1023) / 1024;
  int lo = tid*chunk, hi = min(lo+chunk, N);
  int s = 0;
  for (int i = lo; i < hi; ++i) s += deg[i];
  part[tid] = s;
  __syncthreads();
  for (int d = 1; d < 1024; d <<= 1){
    int v = (tid >= d) ? part[tid-d] : 0;
    __syncthreads();
    part[tid] += v;
    __syncthreads();
  }
  int pref = (tid == 0) ? 0 : part[tid-1];
  for (int i = lo; i < hi; ++i){ offs[i] = pref; pref += deg[i]; }
  if (tid == 1023) offs[N] = part[1023];
}

__global__ void fill_k(const int* __restrict__ atoms, const int* __restrict__ offs,
                       int* __restrict__ cursor, int* __restrict__ rows, int n){
  int r = blockIdx.x*256 + threadIdx.x;
  if (r < n){ int a = atoms[r]; rows[offs[a] + atomicAdd(&cursor[a],1)] = r; }
}

// ---------------- gather stages (CSR, no atomics) ----------------
template<int CW, int RDIV, int ACC, int INB, int OUTB>
__global__ void gath_k(const void* __restrict__ srcv, const int* __restrict__ offs,
                       const int* __restrict__ rows, void* __restrict__ dstv,
                       int OS, int OFF){
  int t = blockIdx.x*256 + threadIdx.x;
  if (t >= NNODES*CW) return;
  int n = t / CW, ch = t - n*CW;
  int o = offs[n], e = offs[n+1];
  float s = 0.f;
  for (int i = o; i < e; ++i){
    int r = rows[i];
    size_t si = (size_t)(r / RDIV) * CW + ch;
    s += INB ? bs2f(((const short*)srcv)[si]) : ((const float*)srcv)[si];
  }
  size_t di = (size_t)n*OS + OFF + ch;
  if (OUTB){ short* d = (short*)dstv; d[di] = f2bs((ACC ? bs2f(d[di]) : 0.f) + s); }
  else     { float* d = (float*)dstv; d[di] = (ACC ? d[di] : 0.f) + s; }
}

// S1[c][ch] = sum_j node_e[atom[c*R+j]][ch]   (fp32)
template<int R>
__global__ void s1_k(const float* __restrict__ node_e, const int* __restrict__ atoms,
                     float* __restrict__ S1, int C){
  int t = blockIdx.x*256 + threadIdx.x;
  if (t >= C*64) return;
  int c = t >> 6, ch = t & 63;
  const int* ap = atoms + c*R;
  float s = 0.f;
  #pragma unroll
  for (int j = 0; j < R; ++j) s += node_e[(size_t)ap[j]*64 + ch];
  S1[t] = s;
}

// n5h[n][0:64] = deg[n]*node_e[n]  (bf16 out)
__global__ void n5lo_k(const float* __restrict__ node_e, const int* __restrict__ offs,
                       short* __restrict__ n5h){
  int t = blockIdx.x*256 + threadIdx.x;
  if (t >= NNODES*64) return;
  int n = t >> 6, ch = t & 63;
  float d = (float)(offs[n+1] - offs[n]);
  n5h[(size_t)n*128 + ch] = f2bs(d * node_e[(size_t)n*64 + ch]);
}

// S2h[c][ch] = sum_j n5h[atom[c*R+j]][ch]  (bf16 in/out, fp32 sum)
template<int R>
__global__ void s2_k(const short* __restrict__ n5h, const int* __restrict__ atoms,
                     short* __restrict__ S2h, int C){
  int t = blockIdx.x*256 + threadIdx.x;
  if (t >= C*128) return;
  int c = t >> 7, ch = t & 127;
  const int* ap = atoms + c*R;
  float s = 0.f;
  #pragma unroll
  for (int j = 0; j < R; ++j) s += bs2f(n5h[(size_t)ap[j]*128 + ch]);
  S2h[t] = f2bs(s);
}

// nodeC_h[n][0:128] = deg5*n5_5 + deg6*n5_6
__global__ void nc0_k(const short* __restrict__ n5, const short* __restrict__ n6,
                      const int* __restrict__ o5, const int* __restrict__ o6,
                      short* __restrict__ nodeC){
  int t = blockIdx.x*256 + threadIdx.x;
  if (t >= NNODES*128) return;
  int n = t >> 7;
  float d5 = (float)(o5[n+1]-o5[n]), d6 = (float)(o6[n+1]-o6[n]);
  nodeC[(size_t)n*320 + (t & 127)] = f2bs(d5*bs2f(n5[t]) + d6*bs2f(n6[t]));
}

// fp32 -> bf16 stream convert (n4 = count/4)
__global__ void f2h_k(const float* __restrict__ src, short* __restrict__ dst, int n4){
  int t = blockIdx.x*256 + threadIdx.x;
  if (t >= n4) return;
  float4 v = ((const float4*)src)[t];
  short4 o; o.x=f2bs(v.x); o.y=f2bs(v.y); o.z=f2bs(v.z); o.w=f2bs(v.w);
  ((short4*)dst)[t] = o;
}

// WT[n][k] = bf16(W[k][n]);  W fp32 [K][N], N=1<<logN
__global__ void tr_k(const float* __restrict__ W, short* __restrict__ WT, int K, int logN){
  int t = blockIdx.x*256 + threadIdx.x;
  if (t >= (K << logN)) return;
  int k = t >> logN, n = t & ((1<<logN)-1);
  WT[(size_t)n*K + k] = f2bs(W[t]);
}

// scale/shift for BN fusion: y = scale[ch]*x + shift[ch]
__global__ void mkscale_k(const float* __restrict__ ssum, const float* __restrict__ ssq,
                          const float* __restrict__ g, const float* __restrict__ b,
                          float* __restrict__ scale, float* __restrict__ shift, int M){
  int ch = threadIdx.x;
  float inv  = 1.f / (float)M;
  float mean = ssum[ch]*inv;
  float var  = fmaxf(ssq[ch]*inv - mean*mean, 0.f);
  float sc   = g[ch] * rsqrtf(var + 1e-5f);
  scale[ch] = sc; shift[ch] = b[ch] - mean*sc;
}

// final BatchNorm+ReLU on fp32 d_out (C=64), in place
__global__ void bnf_k(float* __restrict__ X, const float* __restrict__ ssum,
                      const float* __restrict__ ssq, const float* __restrict__ g,
                      const float* __restrict__ b, int M){
  int t = blockIdx.x*256 + threadIdx.x;
  if (t >= M*64) return;
  int ch = t & 63;
  float inv  = 1.f / (float)M;
  float mean = ssum[ch]*inv;
  float var  = fmaxf(ssq[ch]*inv - mean*mean, 0.f);
  float sc   = g[ch] * rsqrtf(var + 1e-5f);
  X[t] = fmaxf(sc*X[t] + (b[ch] - mean*sc), 0.f);
}

// ---------------- MFMA GEMM ----------------
// Round-2 change: stats epilogue no longer does per-wave global atomics
// (1.9M atomic lane-ops to 16 cache lines serialized the whole kernel at
// ~253us with all pipes <4% busy). Now: per-block LDS reduction into
// slice-buffer 0 (dead in the final K-iteration since NK is even), then
// ONE atomicAdd per channel per block -> 16x less per-line atomic traffic.
// LOADER 1: edge rows  [ef_h(64) | nodeC_h[aS](320) | shfl-combined(320)], KC=704
// LOADER 2: cycle rows [n5h[aS](128) | S2h[m/RDIV](128) | featsh(64)],    KC=320
// LOADER 3: bf16 A with fused per-k affine+ReLU (BN1), KC=128
template<int LOADER, int NT, int OUTF32, int KC, int RDIV>
__global__ __launch_bounds__(256) void gemm_k(
    const short* __restrict__ A, const short* __restrict__ G0,
    const short* __restrict__ G1, const float* __restrict__ F0,
    const float* __restrict__ F1, const int* __restrict__ atoms,
    const short* __restrict__ BT, void* __restrict__ CoutV,
    float* __restrict__ ssum, float* __restrict__ ssq, int M)
{
  constexpr int NK = KC/32;          // k-slices
  static_assert(NK % 2 == 0, "final MFMA must read LDS buffer 1 (sred aliases buffer 0)");
  constexpr int NC = NT*16;          // output cols = BT rows staged
  constexpr int CH = (NC*4)/256;     // 16B chunks per thread per slice
  __shared__ short lds[2*NC*32];     // 2 slice buffers

  const int wv   = threadIdx.x >> 6;
  const int lane = threadIdx.x & 63;
  const int row0 = blockIdx.x*64 + wv*16;
  const int l15 = lane & 15, quad = lane >> 4;
  // whole waves can be out of range; they still participate in staging,
  // barriers and the stats reduction (contributing zeros)
  const bool act = (row0 < M);
  const int m = act ? (row0 + l15) : 0;

  int aS = 0, cyc = 0;
  if (LOADER == 1) aS = act ? atoms[m] : 0;
  if (LOADER == 2) { aS = act ? atoms[m] : 0; cyc = m / RDIV; }

  // ---- A prefetch: issue every gathered fragment load now ----
  constexpr int NLD = (LOADER==1) ? 12 : (LOADER==2 ? 10 : NK);
  short8 af[NLD];
  if (act) {
    #pragma unroll
    for (int kt = 0; kt < NLD; ++kt) {
      const int k0 = kt*32 + quad*8;
      if (LOADER == 1) {
        if (kt < 2) af[kt] = *reinterpret_cast<const short8*>(A + (size_t)m*64 + k0);
        else        af[kt] = *reinterpret_cast<const short8*>(G0 + (size_t)aS*320 + (k0-64));
      } else if (LOADER == 2) {
        if (kt < 4)      af[kt] = *reinterpret_cast<const short8*>(G0 + (size_t)aS*128 + k0);
        else if (kt < 8) af[kt] = *reinterpret_cast<const short8*>(G1 + (size_t)cyc*128 + (k0-128));
        else             af[kt] = *reinterpret_cast<const short8*>(A + (size_t)m*64 + (k0-256));
      } else { // LOADER 3: raw rows, BN affine applied at use
        af[kt] = *reinterpret_cast<const short8*>(A + (size_t)m*KC + k0);
      }
    }
  }

  // ---- B slice staging helpers (all 256 threads) ----
  auto stage_load = [&](int kt, short8* r){
    #pragma unroll
    for (int i = 0; i < CH; ++i) {
      int id = i*256 + (int)threadIdx.x;        // chunk id: n = id>>2, c = id&3
      r[i] = *reinterpret_cast<const short8*>(BT + (size_t)(id>>2)*KC + kt*32 + (id&3)*8);
    }
  };
  auto stage_write = [&](int b, short8* r){
    #pragma unroll
    for (int i = 0; i < CH; ++i) {
      int id = i*256 + (int)threadIdx.x;
      int n = id>>2, c = id&3;
      *reinterpret_cast<short8*>(&lds[b*NC*32 + n*32 + ((c ^ ((n>>1)&3)))*8]) = r[i];
    }
  };

  f32x4 acc[NT];
  #pragma unroll
  for (int nt = 0; nt < NT; ++nt) acc[nt] = (f32x4){0.f,0.f,0.f,0.f};

  // depth-2 pipeline: slices kt and kt+1 in flight in registers
  short8 sr0[CH], sr1[CH], sr2[CH];
  stage_load(0, sr0);
  if (NK > 1) stage_load(1, sr1);

  #pragma unroll
  for (int kt = 0; kt < NK; ++kt) {
    short8* cur = (kt % 3 == 0) ? sr0 : ((kt % 3 == 1) ? sr1 : sr2);
    stage_write(kt & 1, cur);
    if (kt + 2 < NK) {
      short8* nxt = ((kt+2) % 3 == 0) ? sr0 : (((kt+2) % 3 == 1) ? sr1 : sr2);
      stage_load(kt + 2, nxt);
    }
    __syncthreads();

    if (act) {
      const int k0 = kt*32 + quad*8;
      short8 afk;
      {
        short8 base = af[(kt < NLD) ? kt : (kt - 10)];
        if (LOADER == 3) {
          float sc[8], sh[8];
          const float4* sp = reinterpret_cast<const float4*>(F0 + k0);
          const float4* hp = reinterpret_cast<const float4*>(F1 + k0);
          *reinterpret_cast<float4*>(&sc[0]) = sp[0]; *reinterpret_cast<float4*>(&sc[4]) = sp[1];
          *reinterpret_cast<float4*>(&sh[0]) = hp[0]; *reinterpret_cast<float4*>(&sh[4]) = hp[1];
          #pragma unroll
          for (int j = 0; j < 8; ++j) afk[j] = f2bs(fmaxf(sc[j]*bs2f(base[j]) + sh[j], 0.f));
        } else if (LOADER == 1 && kt >= 12) {
          afk = combine_pair(base);
        } else {
          afk = base;
        }
      }
      #pragma unroll
      for (int nt = 0; nt < NT; ++nt) {
        const int n = nt*16 + l15;
        const short8 bfg = *reinterpret_cast<const short8*>(
            &lds[(kt&1)*NC*32 + n*32 + ((quad ^ ((n>>1)&3)))*8]);
        acc[nt] = __builtin_amdgcn_mfma_f32_16x16x32_bf16(afk, bfg, acc[nt], 0, 0, 0);
      }
    }
  }

  // ---- C write + per-block stats reduction ----
  // sred aliases LDS slice-buffer 0; final kt (= NK-1, odd) read buffer 1,
  // so no barrier is needed before writing it. [2 arrays][4 waves][NC ch]
  float* sred = reinterpret_cast<float*>(lds);

  #pragma unroll
  for (int nt = 0; nt < NT; ++nt) {
    float ps = 0.f, pq = 0.f;
    if (act) {
      #pragma unroll
      for (int rg = 0; rg < 4; ++rg) {
        float v = acc[nt][rg];                     // D[row=quad*4+rg][col=l15]
        int r = row0 + quad*4 + rg;
        if (OUTF32) ((float*)CoutV)[(size_t)r*NC + nt*16 + l15] = v;
        else        ((short*)CoutV)[(size_t)r*NC + nt*16 + l15] = f2bs(v);
        ps += v; pq += v*v;
      }
    }
    ps += __shfl_xor(ps, 16); pq += __shfl_xor(pq, 16);
    ps += __shfl_xor(ps, 32); pq += __shfl_xor(pq, 32);
    if (lane < 16) {                               // quad == 0
      sred[wv*NC + nt*16 + lane]        = ps;
      sred[4*NC + wv*NC + nt*16 + lane] = pq;
    }
  }
  __syncthreads();
  for (int ch = threadIdx.x; ch < NC; ch += 256) {
    float s = sred[ch] + sred[NC + ch] + sred[2*NC + ch] + sred[3*NC + ch];
    float q = sred[4*NC + ch] + sred[5*NC + ch] + sred[6*NC + ch] + sred[7*NC + ch];
    atomicAdd(&ssum[ch], s);
    atomicAdd(&ssq[ch], q);
  }
}

static inline int cdiv(int a, int b){ return (a + b - 1)/b; }

extern "C" void kernel_launch(void* const* d_in, const int* in_sizes, int n_in,
                              void* d_out, int out_size, void* d_ws, size_t ws_size,
                              hipStream_t stream)
{
  const float* edge_feats = (const float*)d_in[0];
  const float* c5_feats   = (const float*)d_in[1];
  const float* c6_feats   = (const float*)d_in[2];
  const int*   e_atoms    = (const int*)d_in[3];
  const int*   c5_atoms   = (const int*)d_in[4];
  const int*   c6_atoms   = (const int*)d_in[5];
  const float* eW1 = (const float*)d_in[6];
  const float* eg1 = (const float*)d_in[7];
  const float* eb1 = (const float*)d_in[8];
  const float* eW2 = (const float*)d_in[9];
  const float* eg2 = (const float*)d_in[10];
  const float* eb2 = (const float*)d_in[11];
  const float* cW1 = (const float*)d_in[12];
  const float* cg1 = (const float*)d_in[13];
  const float* cb1 = (const float*)d_in[14];
  const float* cW2 = (const float*)d_in[15];
  const float* cg2 = (const float*)d_in[16];
  const float* cb2 = (const float*)d_in[17];
  float* out = (float*)d_out;
  (void)in_sizes; (void)n_in; (void)out_size; (void)ws_size;

  char* w = (char*)d_ws;
  auto alloc = [&](size_t bytes) -> char* {
    char* p = w; w += (bytes + 255) & ~(size_t)255; return p;
  };

  // ---- zero zone (~1 MB): histograms, cursors, stats ----
  char* zbase = w;
  int*  deg_e = (int*)alloc(NNODES*4);
  int*  deg_5 = (int*)alloc(NNODES*4);
  int*  deg_6 = (int*)alloc(NNODES*4);
  int*  cur_e = (int*)alloc(NNODES*4);
  int*  cur_5 = (int*)alloc(NNODES*4);
  int*  cur_6 = (int*)alloc(NNODES*4);
  float* stats = (float*)alloc(1152*4);
  size_t zbytes = (size_t)(w - zbase);

  float* se1 = stats;        float* qe1 = stats + 128;
  float* se2 = stats + 256;  float* qe2 = stats + 320;
  float* s51 = stats + 384;  float* q51 = stats + 512;
  float* s52 = stats + 640;  float* q52 = stats + 704;
  float* s61 = stats + 768;  float* q61 = stats + 896;
  float* s62 = stats + 1024; float* q62 = stats + 1088;

  // ---- write-before-read buffers ----
  int* offs_e = (int*)alloc((NNODES+1)*4);
  int* offs_5 = (int*)alloc((NNODES+1)*4);
  int* offs_6 = (int*)alloc((NNODES+1)*4);
  int* rows_e = (int*)alloc((size_t)EROWS*4);
  int* rows_5 = (int*)alloc((size_t)C5ROWS*4);
  int* rows_6 = (int*)alloc((size_t)C6ROWS*4);
  short* nodeC_h = (short*)alloc((size_t)NNODES*320*2);   // 25.6 MB
  short* n5_5h   = (short*)alloc((size_t)NNODES*128*2);   // 10.24 MB
  short* n5_6h   = (short*)alloc((size_t)NNODES*128*2);
  short* S2_5h   = (short*)alloc((size_t)NCYC5*128*2);    // 7.68 MB
  short* S2_6h   = (short*)alloc((size_t)NCYC6*128*2);    // 6.4 MB
  short* ef_h    = (short*)alloc((size_t)EROWS*64*2);     // 15.36 MB
  short* c5f_h   = (short*)alloc((size_t)C5ROWS*64*2);    // 19.2 MB
  short* c6f_h   = (short*)alloc((size_t)C6ROWS*64*2);    // 19.2 MB
  short* eW1T    = (short*)alloc((size_t)128*704*2);
  short* cW1T    = (short*)alloc((size_t)128*320*2);
  short* eW2T    = (short*)alloc((size_t)64*128*2);
  short* cW2T    = (short*)alloc((size_t)64*128*2);
  float* scsh    = (float*)alloc(768*4);                  // 3x (scale128, shift128)
  float* sc_e = scsh;       float* sh_e = scsh + 128;
  float* sc_5 = scsh + 256; float* sh_5 = scsh + 384;
  float* sc_6 = scsh + 512; float* sh_6 = scsh + 640;
  // h1 region (38.4 MB) shared by 3 MLPs; phase-1 fp32 temporaries alias it
  char*  h1reg = alloc((size_t)C5ROWS*128*2);
  short* h1    = (short*)h1reg;
  float* node_e = (float*)h1reg;                                          // 10.24 MB
  float* S1_5   = (float*)(h1reg + (size_t)NNODES*64*4);                  // 7.68 MB
  float* S1_6   = (float*)(h1reg + (size_t)NNODES*64*4 + (size_t)NCYC5*64*4); // 6.4 MB
  // total ws ~156 MB

  hipMemsetAsync(zbase, 0, zbytes, stream);

  // ---- CSR build ----
  hist_k<<<cdiv(EROWS,256),256,0,stream>>>(e_atoms, deg_e, EROWS);
  hist_k<<<cdiv(C5ROWS,256),256,0,stream>>>(c5_atoms, deg_5, C5ROWS);
  hist_k<<<cdiv(C6ROWS,256),256,0,stream>>>(c6_atoms, deg_6, C6ROWS);
  scan3_k<<<3,1024,0,stream>>>(deg_e, deg_5, deg_6, offs_e, offs_5, offs_6);
  fill_k<<<cdiv(EROWS,256),256,0,stream>>>(e_atoms, offs_e, cur_e, rows_e, EROWS);
  fill_k<<<cdiv(C5ROWS,256),256,0,stream>>>(c5_atoms, offs_5, cur_5, rows_5, C5ROWS);
  fill_k<<<cdiv(C6ROWS,256),256,0,stream>>>(c6_atoms, offs_6, cur_6, rows_6, C6ROWS);

  // ---- bf16 copies of GEMM A-row sources ----
  f2h_k<<<cdiv(EROWS*16,256),256,0,stream>>>(edge_feats, ef_h, EROWS*16);
  f2h_k<<<cdiv(C5ROWS*16,256),256,0,stream>>>(c5_feats, c5f_h, C5ROWS*16);
  f2h_k<<<cdiv(C6ROWS*16,256),256,0,stream>>>(c6_feats, c6f_h, C6ROWS*16);

  // ---- phase 1: node/cycle aggregates (gather, no atomics) ----
  gath_k<64,1,0,0,0><<<cdiv(NNODES*64,256),256,0,stream>>>(edge_feats, offs_e, rows_e, node_e, 64, 0);
  s1_k<5><<<cdiv(NCYC5*64,256),256,0,stream>>>(node_e, c5_atoms, S1_5, NCYC5);
  s1_k<6><<<cdiv(NCYC6*64,256),256,0,stream>>>(node_e, c6_atoms, S1_6, NCYC6);
  n5lo_k<<<cdiv(NNODES*64,256),256,0,stream>>>(node_e, offs_5, n5_5h);
  n5lo_k<<<cdiv(NNODES*64,256),256,0,stream>>>(node_e, offs_6, n5_6h);
  gath_k<64,5,0,0,1><<<cdiv(NNODES*64,256),256,0,stream>>>(S1_5, offs_5, rows_5, n5_5h, 128, 64);
  gath_k<64,6,0,0,1><<<cdiv(NNODES*64,256),256,0,stream>>>(S1_6, offs_6, rows_6, n5_6h, 128, 64);
  s2_k<5><<<cdiv(NCYC5*128,256),256,0,stream>>>(n5_5h, c5_atoms, S2_5h, NCYC5);
  s2_k<6><<<cdiv(NCYC6*128,256),256,0,stream>>>(n5_6h, c6_atoms, S2_6h, NCYC6);
  nc0_k<<<cdiv(NNODES*128,256),256,0,stream>>>(n5_5h, n5_6h, offs_5, offs_6, nodeC_h);
  gath_k<128,5,0,1,1><<<cdiv(NNODES*128,256),256,0,stream>>>(S2_5h, offs_5, rows_5, nodeC_h, 320, 128);
  gath_k<128,6,1,1,1><<<cdiv(NNODES*128,256),256,0,stream>>>(S2_6h, offs_6, rows_6, nodeC_h, 320, 128);
  gath_k<64,1,0,0,1><<<cdiv(NNODES*64,256),256,0,stream>>>(c5_feats, offs_5, rows_5, nodeC_h, 320, 256);
  gath_k<64,1,1,0,1><<<cdiv(NNODES*64,256),256,0,stream>>>(c6_feats, offs_6, rows_6, nodeC_h, 320, 256);

  // ---- weight transposes ----
  tr_k<<<cdiv(704*128,256),256,0,stream>>>(eW1, eW1T, 704, 7);
  tr_k<<<cdiv(320*128,256),256,0,stream>>>(cW1, cW1T, 320, 7);
  tr_k<<<cdiv(128*64,256),256,0,stream>>>(eW2, eW2T, 128, 6);
  tr_k<<<cdiv(128*64,256),256,0,stream>>>(cW2, cW2T, 128, 6);

  float* out_e = out;
  float* out_5 = out + (size_t)EROWS*64;
  float* out_6 = out + (size_t)(EROWS + C5ROWS)*64;

  // ---- edge MLP ----
  gemm_k<1,8,0,704,1><<<cdiv(EROWS,64),256,0,stream>>>(ef_h, nodeC_h, nullptr, nullptr, nullptr,
                                                       e_atoms, eW1T, h1, se1, qe1, EROWS);
  mkscale_k<<<1,128,0,stream>>>(se1, qe1, eg1, eb1, sc_e, sh_e, EROWS);
  gemm_k<3,4,1,128,1><<<cdiv(EROWS,64),256,0,stream>>>(h1, nullptr, nullptr, sc_e, sh_e,
                                                       nullptr, eW2T, out_e, se2, qe2, EROWS);
  bnf_k<<<cdiv(EROWS*64,256),256,0,stream>>>(out_e, se2, qe2, eg2, eb2, EROWS);

  // ---- cycle5 MLP ----
  gemm_k<2,8,0,320,5><<<cdiv(C5ROWS,64),256,0,stream>>>(c5f_h, n5_5h, S2_5h, nullptr, nullptr,
                                                        c5_atoms, cW1T, h1, s51, q51, C5ROWS);
  mkscale_k<<<1,128,0,stream>>>(s51, q51, cg1, cb1, sc_5, sh_5, C5ROWS);
  gemm_k<3,4,1,128,1><<<cdiv(C5ROWS,64),256,0,stream>>>(h1, nullptr, nullptr, sc_5, sh_5,
                                                        nullptr, cW2T, out_5, s52, q52, C5ROWS);
  bnf_k<<<cdiv(C5ROWS*64,256),256,0,stream>>>(out_5, s52, q52, cg2, cb2, C5ROWS);

  // ---- cycle6 MLP ----
  gemm_k<2,8,0,320,6><<<cdiv(C6ROWS,64),256,0,stream>>>(c6f_h, n5_6h, S2_6h, nullptr, nullptr,
                                                        c6_atoms, cW1T, h1, s61, q61, C6ROWS);
  mkscale_k<<<1,128,0,stream>>>(s61, q61, cg1, cb1, sc_6, sh_6, C6ROWS);
  gemm_k<3,4,1,128,1><<<cdiv(C6ROWS,64),256,0,stream>>>(h1, nullptr, nullptr, sc_6, sh_6,
                                                        nullptr, cW2T, out_6, s62, q62, C6ROWS);
  bnf_k<<<cdiv(C6ROWS*64,256),256,0,stream>>>(out_6, s62, q62, cg2, cb2, C6ROWS);
}